// Round 14
// baseline (596.100 us; speedup 1.0000x reference)
//
#include <hip/hip_runtime.h>

typedef unsigned short u16;
typedef __bf16 bf16x8 __attribute__((ext_vector_type(8)));
typedef float floatx4 __attribute__((ext_vector_type(4)));

// dims: B=4 N=2048 E=1600 R=448 H=512 P=2 NH=4 DH=128 FF=2048
// f32 in/out; bf16 MFMA GEMMs w/ f32 accum; flash-fused attention.
// GEMMs: global_load_lds width=16, double-buffered LDS, 1 barrier/K-step.
// N=512 GEMMs (Wo, W2) are SPLIT-K=2: half 0 -> tmp_f (bias[+res]+partial),
// half 1 -> tmp2_f (raw partial); the following k_ln sums both (free merge).
// Attn: round-6 form + setprio. LN/prep vectorized. LN2(j=1) -> d_out.

__device__ __forceinline__ float bf2f(u16 u) {
  union { unsigned int i; float f; } c; c.i = ((unsigned int)u) << 16; return c.f;
}
__device__ __forceinline__ u16 f2bf(float f) {
  union { unsigned int i; float f; } c; c.f = f;
  unsigned int i = c.i;
  return (u16)((i + 0x7FFFu + ((i >> 16) & 1u)) >> 16);
}

// async global->LDS, 16B per lane. dst must be wave-uniform (HW adds lane*16).
__device__ __forceinline__ void gload16(const u16* __restrict__ g, u16* l) {
  __builtin_amdgcn_global_load_lds(
      (const __attribute__((address_space(1))) unsigned int*)g,
      (__attribute__((address_space(3))) unsigned int*)l, 16, 0, 0);
}

// ---------------- bf16 TN GEMM, 128x128 tile, dbuf ----------------
// EPI: 1 +bias, 2 +bias+PReLU, 3 +bias+res(f32). FOUT: 1 f32 out, 0 bf16 out.
// SEG3: bias selected from {bias,bias2,bias3} by 512-col segment (fused QKV).
template <int EPI, int FOUT, int SEG3>
__global__ __launch_bounds__(256, 3) void gemm_tn(
    const u16* __restrict__ A, const u16* __restrict__ Bt, void* __restrict__ Cv,
    const float* __restrict__ bias, const float* __restrict__ bias2,
    const float* __restrict__ bias3, const float* __restrict__ alpha,
    const float* __restrict__ res, int K, int lda, int ldb, int ldc) {
  __shared__ __align__(16) u16 As[2][128 * 32];   // 8KB x2
  __shared__ __align__(16) u16 Bs[2][128 * 32];   // 8KB x2  -> 32KB total

  const int tid = threadIdx.x;
  const int w = tid >> 6, lane = tid & 63;
  const int quad = lane >> 4, l16 = lane & 15;
  const int wm = w & 1, wn = w >> 1;

  // slot s (=0..511) covers LDS bytes s*16; row s>>2, col (s&3)*8 elems (pitch 32)
  const int slot0 = w * 128 + lane;
  const int slot1 = slot0 + 64;
  const u16* pA0 = A + (long)(blockIdx.x * 128 + (slot0 >> 2)) * lda + (slot0 & 3) * 8;
  const u16* pA1 = A + (long)(blockIdx.x * 128 + (slot1 >> 2)) * lda + (slot1 & 3) * 8;
  const u16* pB0 = Bt + (long)(blockIdx.y * 128 + (slot0 >> 2)) * ldb + (slot0 & 3) * 8;
  const u16* pB1 = Bt + (long)(blockIdx.y * 128 + (slot1 >> 2)) * ldb + (slot1 & 3) * 8;
  const int woff0 = w * 1024;          // wave-uniform dst offsets (u16 units)
  const int woff1 = woff0 + 512;

  const floatx4 z4 = {0.f, 0.f, 0.f, 0.f};
  floatx4 acc[4][4];
#pragma unroll
  for (int i = 0; i < 4; i++)
#pragma unroll
    for (int j = 0; j < 4; j++) acc[i][j] = z4;

  // prologue: stage tile 0 into buf 0
  gload16(pA0, &As[0][woff0]);
  gload16(pA1, &As[0][woff1]);
  gload16(pB0, &Bs[0][woff0]);
  gload16(pB1, &Bs[0][woff1]);
  pA0 += 32; pA1 += 32; pB0 += 32; pB1 += 32;
  __syncthreads();   // drains vmcnt -> buf0 visible

  int p = 0;
  for (int k0 = 0; k0 < K; k0 += 32) {
    if (k0 + 32 < K) {   // prefetch next tile into other buffer (issue-early)
      gload16(pA0, &As[p ^ 1][woff0]);
      gload16(pA1, &As[p ^ 1][woff1]);
      gload16(pB0, &Bs[p ^ 1][woff0]);
      gload16(pB1, &Bs[p ^ 1][woff1]);
      pA0 += 32; pA1 += 32; pB0 += 32; pB1 += 32;
    }

    bf16x8 af[4], bv[4];
#pragma unroll
    for (int mi = 0; mi < 4; mi++)
      af[mi] = *(const bf16x8*)&As[p][(wm * 64 + mi * 16 + l16) * 32 + quad * 8];
#pragma unroll
    for (int ni = 0; ni < 4; ni++)
      bv[ni] = *(const bf16x8*)&Bs[p][(wn * 64 + ni * 16 + l16) * 32 + quad * 8];
#pragma unroll
    for (int mi = 0; mi < 4; mi++)
#pragma unroll
      for (int ni = 0; ni < 4; ni++)
        acc[mi][ni] = __builtin_amdgcn_mfma_f32_16x16x32_bf16(af[mi], bv[ni], acc[mi][ni], 0, 0, 0);

    __syncthreads();   // drains prefetch vmcnt + all reads of buf p done
    p ^= 1;
  }

  const float* bptr = bias;
  if (SEG3) {
    const int seg = blockIdx.y >> 2;
    bptr = (seg == 0) ? bias : ((seg == 1) ? bias2 : bias3);
  }
  const long crow0 = (long)blockIdx.x * 128;
  const int ncol0 = blockIdx.y * 128 + wn * 64 + l16;
#pragma unroll
  for (int mi = 0; mi < 4; mi++) {
#pragma unroll
    for (int r = 0; r < 4; r++) {
      const int m = wm * 64 + mi * 16 + quad * 4 + r;
      const long rowbase = (crow0 + m) * (long)ldc;
      const float* rrow = (EPI == 3) ? (res + rowbase) : nullptr;
#pragma unroll
      for (int ni = 0; ni < 4; ni++) {
        const int n = ncol0 + ni * 16;
        float vv = acc[mi][ni][r] + bptr[SEG3 ? (n & 511) : n];
        if (EPI == 2) { if (vv < 0.f) vv *= alpha[n]; }
        if (EPI == 3) vv += rrow[n];
        if (FOUT) ((float*)Cv)[rowbase + n] = vv;
        else ((u16*)Cv)[rowbase + n] = f2bf(vv);
      }
    }
  }
}

// ---------------- bf16 TN GEMM, 128x64 tile, dbuf, optional split-K=2 ----------------
// SK=1: blockIdx.z selects K-half; z=0 writes bias[+res]+partial to Cv (f32),
// z=1 writes raw partial to Cv2 (f32). Consumer sums Cv+Cv2.
template <int EPI, int FOUT, int SK>
__global__ __launch_bounds__(256, 3) void gemm_tn64(
    const u16* __restrict__ A, const u16* __restrict__ Bt, void* __restrict__ Cv,
    void* __restrict__ Cv2, const float* __restrict__ bias,
    const float* __restrict__ alpha, const float* __restrict__ res,
    int K, int lda, int ldb, int ldc) {
  __shared__ __align__(16) u16 As[2][128 * 32];   // 8KB x2
  __shared__ __align__(16) u16 Bs[2][64 * 32];    // 4KB x2  -> 24KB total

  const int tid = threadIdx.x;
  const int w = tid >> 6, lane = tid & 63;
  const int quad = lane >> 4, l16 = lane & 15;

  const int Kh = SK ? (K >> 1) : K;
  if (SK) {
    const int koff = blockIdx.z * Kh;
    A += koff;            // shift K-window (row-major, lda strides rows)
    Bt += koff;
  }

  const int rA0 = tid >> 2, cA = (tid & 3) * 8;   // A slots: tid, tid+256 (linear)
  const int rA1 = rA0 + 64;
  const u16* pA0 = A + (long)(blockIdx.x * 128 + rA0) * lda + cA;
  const u16* pA1 = A + (long)(blockIdx.x * 128 + rA1) * lda + cA;
  const u16* pB  = Bt + (long)(blockIdx.y * 64 + rA0) * ldb + cA;  // rA0<64 covers B
  const int aoff0 = w * 512;           // wave-uniform dst offsets (u16 units)
  const int aoff1 = aoff0 + 2048;
  const int boff  = w * 512;

  const floatx4 z4 = {0.f, 0.f, 0.f, 0.f};
  floatx4 acc[2][4];
#pragma unroll
  for (int i = 0; i < 2; i++)
#pragma unroll
    for (int j = 0; j < 4; j++) acc[i][j] = z4;

  // prologue: stage tile 0 into buf 0
  gload16(pA0, &As[0][aoff0]);
  gload16(pA1, &As[0][aoff1]);
  gload16(pB, &Bs[0][boff]);
  pA0 += 32; pA1 += 32; pB += 32;
  __syncthreads();

  int p = 0;
  for (int k0 = 0; k0 < Kh; k0 += 32) {
    if (k0 + 32 < Kh) {
      gload16(pA0, &As[p ^ 1][aoff0]);
      gload16(pA1, &As[p ^ 1][aoff1]);
      gload16(pB, &Bs[p ^ 1][boff]);
      pA0 += 32; pA1 += 32; pB += 32;
    }

    bf16x8 af[2], bv[4];
#pragma unroll
    for (int mi = 0; mi < 2; mi++)
      af[mi] = *(const bf16x8*)&As[p][(w * 32 + mi * 16 + l16) * 32 + quad * 8];
#pragma unroll
    for (int ni = 0; ni < 4; ni++)
      bv[ni] = *(const bf16x8*)&Bs[p][(ni * 16 + l16) * 32 + quad * 8];
#pragma unroll
    for (int mi = 0; mi < 2; mi++)
#pragma unroll
      for (int ni = 0; ni < 4; ni++)
        acc[mi][ni] = __builtin_amdgcn_mfma_f32_16x16x32_bf16(af[mi], bv[ni], acc[mi][ni], 0, 0, 0);

    __syncthreads();
    p ^= 1;
  }

  const long crow0 = (long)blockIdx.x * 128;
  const int ncol0 = blockIdx.y * 64 + l16;
  const int raw = SK && (blockIdx.z == 1);   // raw-partial half
#pragma unroll
  for (int mi = 0; mi < 2; mi++) {
#pragma unroll
    for (int r = 0; r < 4; r++) {
      const int m = w * 32 + mi * 16 + quad * 4 + r;
      const long rowbase = (crow0 + m) * (long)ldc;
      const float* rrow = (EPI == 3) ? (res + rowbase) : nullptr;
#pragma unroll
      for (int ni = 0; ni < 4; ni++) {
        const int n = ncol0 + ni * 16;
        if (raw) {
          ((float*)Cv2)[rowbase + n] = acc[mi][ni][r];
        } else {
          float vv = acc[mi][ni][r] + bias[n];
          if (EPI == 2) { if (vv < 0.f) vv *= alpha[n]; }
          if (EPI == 3) vv += rrow[n];
          if (FOUT) ((float*)Cv)[rowbase + n] = vv;
          else ((u16*)Cv)[rowbase + n] = f2bf(vv);
        }
      }
    }
  }
}

// ---------------- flash-fused attention (round-6 form + setprio) ----------------
// grid (32 qtiles of 64 rows, 16 bh). Q,K read from fused qkv buffer (ld=1536).
#define LDP 136
__global__ __launch_bounds__(256, 3) void k_attn(
    const u16* __restrict__ qkv, const u16* __restrict__ vt,
    const unsigned* __restrict__ mbits, u16* __restrict__ og) {
  __shared__ __align__(16) u16 KV[128 * LDP];
  __shared__ __align__(16) u16 Pl[64 * LDP];
  __shared__ unsigned Ml[64 * 4];

  const int tid = threadIdx.x;
  const int w = tid >> 6, lane = tid & 63;
  const int quad = lane >> 4, l16 = lane & 15;
  const int qt = blockIdx.x;
  const int z = blockIdx.y;
  const int b = z >> 2, h = z & 3;

  const u16* qbase = qkv + (long)b * 2048 * 1536 + h * 128;        // cols 0..511
  const u16* kbase = qbase + 512;                                   // cols 512..1023
  const u16* vbase = vt + (long)(b * 4 + h) * 128 * 2048;           // [dh][kv]
  const unsigned* mbase = mbits + ((long)b * 2048 + qt * 64) * 64;

  // Q fragments in registers: wave w owns q-rows [w*16, w*16+16)
  bf16x8 qf[4];
#pragma unroll
  for (int ks = 0; ks < 4; ks++)
    qf[ks] = *(const bf16x8*)(qbase +
        (long)(qt * 64 + w * 16 + l16) * 1536 + ks * 32 + quad * 8);

  const floatx4 z4 = {0.f, 0.f, 0.f, 0.f};
  floatx4 Oacc[8];
#pragma unroll
  for (int ni = 0; ni < 8; ni++) Oacc[ni] = z4;
  float mrow[4], lrow[4];
#pragma unroll
  for (int r = 0; r < 4; r++) { mrow[r] = -3.4e38f; lrow[r] = 0.f; }

  const float scale = 0.08838834764831845f;
  const int srow = tid >> 4;            // staging row base
  const int scol = (tid & 15) * 8;      // staging col (elems)

  for (int kt = 0; kt < 16; kt++) {
    __syncthreads();  // prior PV reads of KV/Pl done
    // stage K-tile [kv][dh] + mask words (64 rows x 4 words = 256 = blockDim)
#pragma unroll
    for (int rr = 0; rr < 128; rr += 16)
      *(int4*)&KV[(rr + srow) * LDP + scol] =
          *(const int4*)(kbase + (long)(kt * 128 + rr + srow) * 1536 + scol);
    Ml[tid] = mbase[(tid >> 2) * 64 + kt * 4 + (tid & 3)];
    __syncthreads();

    // QK^T (setprio: favor MFMA-phase waves over co-resident staging blocks)
    floatx4 accS[8];
#pragma unroll
    for (int ni = 0; ni < 8; ni++) accS[ni] = z4;
    __builtin_amdgcn_s_setprio(1);
#pragma unroll
    for (int ks = 0; ks < 4; ks++) {
      bf16x8 bf[8];
#pragma unroll
      for (int ni = 0; ni < 8; ni++)
        bf[ni] = *(const bf16x8*)&KV[(ni * 16 + l16) * LDP + ks * 32 + quad * 8];
#pragma unroll
      for (int ni = 0; ni < 8; ni++)
        accS[ni] = __builtin_amdgcn_mfma_f32_16x16x32_bf16(qf[ks], bf[ni], accS[ni], 0, 0, 0);
    }
    __builtin_amdgcn_s_setprio(0);
    __syncthreads();  // KV reads done -> stage V

    // stage V-tile [dh][kv]
#pragma unroll
    for (int rr = 0; rr < 128; rr += 16)
      *(int4*)&KV[(rr + srow) * LDP + scol] =
          *(const int4*)(vbase + (long)(rr + srow) * 2048 + kt * 128 + scol);

    // online softmax (concurrent with V staging; Pl is wave-private)
#pragma unroll
    for (int r = 0; r < 4; r++) {
      const int rowl = w * 16 + quad * 4 + r;
      float s[8];
      float rmax = -1e30f;
#pragma unroll
      for (int ni = 0; ni < 8; ni++) {
        const unsigned mw = Ml[rowl * 4 + (ni >> 1)];
        const int on = (mw >> ((ni & 1) * 16 + l16)) & 1;
        s[ni] = on ? accS[ni][r] * scale : -1e30f;
        rmax = fmaxf(rmax, s[ni]);
      }
#pragma unroll
      for (int off = 1; off < 16; off <<= 1) rmax = fmaxf(rmax, __shfl_xor(rmax, off, 64));
      const float mnew = fmaxf(mrow[r], rmax);
      const float al = __expf(mrow[r] - mnew);
      float rs = 0.f;
#pragma unroll
      for (int ni = 0; ni < 8; ni++) {
        const float pp = __expf(s[ni] - mnew);
        rs += pp;
        Pl[rowl * LDP + ni * 16 + l16] = f2bf(pp);
      }
#pragma unroll
      for (int off = 1; off < 16; off <<= 1) rs += __shfl_xor(rs, off, 64);
      lrow[r] = lrow[r] * al + rs;
      mrow[r] = mnew;
#pragma unroll
      for (int ni = 0; ni < 8; ni++) Oacc[ni][r] *= al;
    }
    __syncthreads();  // V staged + P written

    // PV (setprio around MFMA cluster)
    __builtin_amdgcn_s_setprio(1);
#pragma unroll
    for (int ks = 0; ks < 4; ks++) {
      bf16x8 bv[8];
#pragma unroll
      for (int ni = 0; ni < 8; ni++)
        bv[ni] = *(const bf16x8*)&KV[(ni * 16 + l16) * LDP + ks * 32 + quad * 8];
      bf16x8 pf = *(const bf16x8*)&Pl[(w * 16 + l16) * LDP + ks * 32 + quad * 8];
#pragma unroll
      for (int ni = 0; ni < 8; ni++)
        Oacc[ni] = __builtin_amdgcn_mfma_f32_16x16x32_bf16(pf, bv[ni], Oacc[ni], 0, 0, 0);
    }
    __builtin_amdgcn_s_setprio(0);
  }

  // epilogue: divide by l, store o[b,q,h,dh] bf16
#pragma unroll
  for (int r = 0; r < 4; r++) {
    const float inv = 1.f / lrow[r];
    const long q = qt * 64 + w * 16 + quad * 4 + r;
#pragma unroll
    for (int ni = 0; ni < 8; ni++)
      og[((long)b * 2048 + q) * 512 + h * 128 + ni * 16 + l16] = f2bf(Oacc[ni][r] * inv);
  }
}

// ---------------- fused prep: build_x(xb, f32x4) + maskpack + weight transposes ------
// Linearized grid: [0,4096) build xb (4 elems/thread); [4096,6144) maskpack
// (grid-strided); [6144,12288) weight-transpose tiles (3072 per P-slab).
__global__ __launch_bounds__(256) void k_prep(
    const float* __restrict__ vents, const int* __restrict__ rels,
    const float* __restrict__ renc, u16* __restrict__ xb,
    const int* __restrict__ adjs, unsigned* __restrict__ bits,
    const float* __restrict__ Wq, const float* __restrict__ Wk,
    const float* __restrict__ Wv, const float* __restrict__ Wo,
    const float* __restrict__ W1, const float* __restrict__ W2,
    u16* __restrict__ wt) {
  __shared__ u16 tile[32][33];
  const int blk = blockIdx.x;
  if (blk < 4096) {
    // build xb, 4 elems/thread (f32x4 read, 4xbf16 packed 8B write)
    const long idx = ((long)blk * 256 + threadIdx.x) * 4;
    const int c = (int)(idx & 511);
    const int row = (int)(idx >> 9);
    const int b = row >> 11, n = row & 2047;
    float4 v4;
    if (n < 1600) v4 = *(const float4*)(vents + ((long)b * 1600 + n) * 512 + c);
    else v4 = *(const float4*)(renc + (long)rels[b * 448 + (n - 1600)] * 512 + c);
    const unsigned lo = (unsigned)f2bf(v4.x) | ((unsigned)f2bf(v4.y) << 16);
    const unsigned hi = (unsigned)f2bf(v4.z) | ((unsigned)f2bf(v4.w) << 16);
    *(uint2*)(xb + idx) = make_uint2(lo, hi);
  } else if (blk < 6144) {
    // maskpack, grid-strided over 262144 waves
    const int lane = threadIdx.x & 63;
    const int wbase = (blk - 4096) * 4 + (threadIdx.x >> 6);
    for (int wid = wbase; wid < 262144; wid += 2048 * 4) {
      const unsigned long long bal = __ballot(adjs[(long)wid * 64 + lane] != 0);
      if (lane == 0) {
        bits[wid * 2] = (unsigned)bal;
        bits[wid * 2 + 1] = (unsigned)(bal >> 32);
      }
    }
  } else {
    // weight transposes: t in [0,6144)
    int t = blk - 6144;
    const int pz = (t >= 3072) ? 1 : 0;
    t -= pz * 3072;
    const float* src;
    u16* dst;
    int ld_s, ld_d, bx, by;
    if (t < 1024) {                       // Wq/Wk/Wv/Wo: 512x512, grid 16x16
      const int wsel = t >> 8, tt = t & 255;
      const float* ws = (wsel == 0) ? Wq : (wsel == 1) ? Wk : (wsel == 2) ? Wv : Wo;
      src = ws + (long)pz * 262144;
      dst = wt + (long)pz * 3145728 + wsel * 262144;
      ld_s = 512; ld_d = 512;
      bx = tt & 15; by = tt >> 4;
    } else if (t < 2048) {                // W1: 512x2048 -> dst [2048][512]
      const int tt = t - 1024;
      src = W1 + (long)pz * 1048576;
      dst = wt + (long)pz * 3145728 + 1048576;
      ld_s = 2048; ld_d = 512;
      bx = tt & 15; by = tt >> 4;         // bx rows (16), by cols (64)
    } else {                              // W2: 2048x512 -> dst [512][2048]
      const int tt = t - 2048;
      src = W2 + (long)pz * 1048576;
      dst = wt + (long)pz * 3145728 + 2097152;
      ld_s = 512; ld_d = 2048;
      bx = tt >> 4; by = tt & 15;         // bx rows (64), by cols (16)
    }
    const int r0 = bx << 5, c0 = by << 5;
    const int tx = threadIdx.x & 31, ty = threadIdx.x >> 5;
#pragma unroll
    for (int i = 0; i < 32; i += 8)
      tile[ty + i][tx] = f2bf(src[(long)(r0 + ty + i) * ld_s + c0 + tx]);
    __syncthreads();
#pragma unroll
    for (int i = 0; i < 32; i += 8)
      dst[(long)(c0 + ty + i) * ld_d + r0 + tx] = tile[tx][ty + i];
  }
}

// ---------------- bf16 transpose for V ----------------
__global__ __launch_bounds__(256) void tr_bf16(const u16* __restrict__ src, u16* __restrict__ dst,
                                               int ld_src, int ld_dst, int zdiv,
                                               long s_out, long s_in, long d_out, long d_in_) {
  __shared__ u16 tile[32][33];
  const int zz = blockIdx.z, zq = zz / zdiv, zr = zz % zdiv;
  src += (long)zq * s_out + (long)zr * s_in;
  dst += (long)zq * d_out + (long)zr * d_in_;
  const int r0 = blockIdx.x << 5, c0 = blockIdx.y << 5;
  const int tx = threadIdx.x & 31, ty = threadIdx.x >> 5;
#pragma unroll
  for (int i = 0; i < 32; i += 8) tile[ty + i][tx] = src[(long)(r0 + ty + i) * ld_src + c0 + tx];
  __syncthreads();
#pragma unroll
  for (int i = 0; i < 32; i += 8) dst[(long)(c0 + ty + i) * ld_dst + r0 + tx] = tile[tx][ty + i];
}

// ---------------- LayerNorm 512 (float2-vectorized, optional 2-input sum) ------------
// SUM2: row = in[row] + in2[row] (split-K partial merge, free in this pass).
template <int WF32, int WBF, int SUM2>
__global__ __launch_bounds__(256) void k_ln(const float* __restrict__ in,
                                            const float* __restrict__ in2,
                                            float* __restrict__ out,
                                            u16* __restrict__ outb,
                                            const float* __restrict__ g, const float* __restrict__ bb) {
  __shared__ float rs[256], rq[256];
  const int row = blockIdx.x, tid = threadIdx.x;
  float2 a = *(const float2*)(in + (long)row * 512 + tid * 2);
  if (SUM2) {
    const float2 a2 = *(const float2*)(in2 + (long)row * 512 + tid * 2);
    a.x += a2.x; a.y += a2.y;
  }
  rs[tid] = a.x + a.y;
  rq[tid] = a.x * a.x + a.y * a.y;
  __syncthreads();
  for (int s = 128; s > 0; s >>= 1) {
    if (tid < s) { rs[tid] += rs[tid + s]; rq[tid] += rq[tid + s]; }
    __syncthreads();
  }
  const float mu = rs[0] * (1.f / 512.f);
  const float var = rq[0] * (1.f / 512.f) - mu * mu;
  const float inv = 1.0f / sqrtf(var + 1e-5f);
  const float2 gg = *(const float2*)(g + tid * 2);
  const float2 b2 = *(const float2*)(bb + tid * 2);
  const float o0 = (a.x - mu) * inv * gg.x + b2.x;
  const float o1 = (a.y - mu) * inv * gg.y + b2.y;
  if (WF32) {
    *(float2*)(out + (long)row * 512 + tid * 2) = make_float2(o0, o1);
  }
  if (WBF) {
    const unsigned pk = (unsigned)f2bf(o0) | ((unsigned)f2bf(o1) << 16);
    *(unsigned*)(outb + (long)row * 512 + tid * 2) = pk;
  }
}

// ---------------- out: fill glob (from gents already in d_out) + emask ----------------
__global__ __launch_bounds__(256) void k_out2(const float* __restrict__ gents,
                                              const int* __restrict__ entlen,
                                              float* __restrict__ out, long out_n) {
  const long G = 2048, GE = 2048 + 4194304;
  const long idx = (long)blockIdx.x * 256 + threadIdx.x;
  if (idx < G) {
    const int b = (int)(idx >> 9), c = (int)(idx & 511);
    int e = entlen[0];
    if (e < 0 || e >= 2048) e = 1600;
    out[idx] = gents[((long)b * 2048 + e) * 512 + c];
  } else {
    const long oi = GE + (idx - G);
    if (oi < out_n) out[oi] = 1.0f;
  }
}

extern "C" void kernel_launch(void* const* d_in, const int* in_sizes, int n_in,
                              void* d_out, int out_size, void* d_ws, size_t ws_size,
                              hipStream_t stream) {
  const int* adjs = (const int*)d_in[0];
  const int* rels = (const int*)d_in[1];
  const float* vents = (const float*)d_in[2];
  const int* entlen = (const int*)d_in[3];
  const float* renc = (const float*)d_in[4];
  const float* Wq = (const float*)d_in[5];
  const float* Wk = (const float*)d_in[6];
  const float* Wv = (const float*)d_in[7];
  const float* Wo = (const float*)d_in[8];
  const float* W1 = (const float*)d_in[9];
  const float* W2 = (const float*)d_in[10];
  const float* bq = (const float*)d_in[11];
  const float* bk = (const float*)d_in[12];
  const float* bv = (const float*)d_in[13];
  const float* bo = (const float*)d_in[14];
  const float* b1 = (const float*)d_in[15];
  const float* b2 = (const float*)d_in[16];
  const float* ln1g = (const float*)d_in[17];
  const float* ln1b = (const float*)d_in[18];
  const float* ln2g = (const float*)d_in[19];
  const float* ln2b = (const float*)d_in[20];
  const float* prelu = (const float*)d_in[21];

  char* base = (char*)d_ws;
  float* tmp2_f = (float*)(base + 0);          // 16 MB (split-K raw partials)
  float* t_f   = (float*)(base + 16777216);    // 16 MB
  float* tmp_f = (float*)(base + 33554432);    // 16 MB
  u16* wt  = (u16*)(base + 50331648);          // 12 MB
  u16* xb  = (u16*)(base + 62914560);          // 8 MB each
  u16* tb  = (u16*)(base + 71303168);
  u16* qkv = (u16*)(base + 79691776);          // 24 MB: [8192][1536] fused Q|K|V
  u16* Vtb = (u16*)(base + 104857600);         // 8 MB
  u16* ob  = (u16*)(base + 113246208);         // 8 MB
  u16* hb  = (u16*)(base + 121634816);         // 32 MB
  unsigned* mbits = (unsigned*)(base + 155189248);  // 2 MB

  float* out_f = (float*)d_out;
  float* gents = out_f + 2048;                 // gents region of d_out

  // fused prep: xb + mask bits + all weight transposes (one dispatch)
  k_prep<<<dim3(12288), 256, 0, stream>>>(vents, rels, renc, xb, adjs, mbits,
                                          Wq, Wk, Wv, Wo, W1, W2, wt);

  for (int j = 0; j < 2; j++) {
    const u16* wqt = wt + (long)j * 3145728;   // [1536 x 512] fused QKV (contiguous)
    const u16* wot = wqt + 786432;
    const u16* w1t = wqt + 1048576;
    const u16* w2t = wqt + 2097152;

    // fused QKV: [8192x512] @ [512x1536] -> qkv[8192][1536], bias per 512-segment
    gemm_tn<1, 0, 1><<<dim3(64, 12), 256, 0, stream>>>(
        xb, wqt, qkv, bq + j * 512, bk + j * 512, bv + j * 512, nullptr, nullptr,
        512, 512, 512, 1536);

    // Vtb[b,h,dh,kv] = qkv[b,kv, 1024 + h*128 + dh]
    tr_bf16<<<dim3(64, 4, 16), 256, 0, stream>>>(qkv + 1024, Vtb, 1536, 2048, 4,
        3145728L, 128L, 1048576L, 262144L);

    // fused attention -> ob
    k_attn<<<dim3(32, 16), 256, 0, stream>>>(qkv, Vtb, mbits, ob);

    // attn_out = ob @ Wo + bo, split-K=2 -> tmp_f (z0: +bias) / tmp2_f (z1: raw)
    gemm_tn64<1, 1, 1><<<dim3(64, 8, 2), 256, 0, stream>>>(
        ob, wot, tmp_f, tmp2_f, bo + j * 512, nullptr, nullptr, 512, 512, 512, 512);
    // t = LN1(tmp + tmp2) -> t_f (residual) + tb (bf16 for W1)
    k_ln<1, 1, 1><<<dim3(8192), 256, 0, stream>>>(tmp_f, tmp2_f, t_f, tb, ln1g + j * 512, ln1b + j * 512);
    // hb(bf16) = PReLU(t @ W1 + b1)
    gemm_tn<2, 0, 0><<<dim3(64, 16), 256, 0, stream>>>(tb, w1t, hb, b1 + j * 2048, nullptr, nullptr, prelu + j * 2048, nullptr, 512, 512, 512, 2048);
    // y = hb @ W2 + b2 + t, split-K=2 -> tmp_f (z0: +bias+res) / tmp2_f (z1: raw)
    gemm_tn64<3, 1, 1><<<dim3(64, 8, 2), 256, 0, stream>>>(
        hb, w2t, tmp_f, tmp2_f, b2 + j * 512, nullptr, t_f, 2048, 2048, 2048, 512);
    // x = LN2(tmp + tmp2): layer 0 -> xb only; layer 1 -> gents in d_out
    if (j == 0)
      k_ln<0, 1, 1><<<dim3(8192), 256, 0, stream>>>(tmp_f, tmp2_f, nullptr, xb, ln2g + j * 512, ln2b + j * 512);
    else
      k_ln<1, 0, 1><<<dim3(8192), 256, 0, stream>>>(tmp_f, tmp2_f, gents, nullptr, ln2g + j * 512, ln2b + j * 512);
  }

  // fill glob (gather from gents already in d_out) + emask
  const long out_n = (long)out_size;
  k_out2<<<dim3(40), 256, 0, stream>>>(gents, entlen, out_f, out_n);
}

// Round 15
// 582.148 us; speedup vs baseline: 1.0240x; 1.0240x over previous
//
#include <hip/hip_runtime.h>

typedef unsigned short u16;
typedef __bf16 bf16x8 __attribute__((ext_vector_type(8)));
typedef float floatx4 __attribute__((ext_vector_type(4)));

// dims: B=4 N=2048 E=1600 R=448 H=512 P=2 NH=4 DH=128 FF=2048
// f32 in/out; bf16 MFMA GEMMs w/ f32 accum; flash-fused attention.
// GEMMs: global_load_lds width=16, double-buffered LDS, 1 barrier/K-step.
// Attn: round-6 form + setprio + XCD-grouped 1-D grid (all 32 q-tiles of a
// bh land on one XCD -> its K/V stays in that XCD's L2; kills 2x over-fetch).
// Split-K REVERTED (r14: -8us). LN/prep vectorized. LN2(j=1) -> d_out.

__device__ __forceinline__ float bf2f(u16 u) {
  union { unsigned int i; float f; } c; c.i = ((unsigned int)u) << 16; return c.f;
}
__device__ __forceinline__ u16 f2bf(float f) {
  union { unsigned int i; float f; } c; c.f = f;
  unsigned int i = c.i;
  return (u16)((i + 0x7FFFu + ((i >> 16) & 1u)) >> 16);
}

// async global->LDS, 16B per lane. dst must be wave-uniform (HW adds lane*16).
__device__ __forceinline__ void gload16(const u16* __restrict__ g, u16* l) {
  __builtin_amdgcn_global_load_lds(
      (const __attribute__((address_space(1))) unsigned int*)g,
      (__attribute__((address_space(3))) unsigned int*)l, 16, 0, 0);
}

// ---------------- bf16 TN GEMM, 128x128 tile, dbuf ----------------
// EPI: 1 +bias, 2 +bias+PReLU, 3 +bias+res(f32). FOUT: 1 f32 out, 0 bf16 out.
// SEG3: bias selected from {bias,bias2,bias3} by 512-col segment (fused QKV).
template <int EPI, int FOUT, int SEG3>
__global__ __launch_bounds__(256, 3) void gemm_tn(
    const u16* __restrict__ A, const u16* __restrict__ Bt, void* __restrict__ Cv,
    const float* __restrict__ bias, const float* __restrict__ bias2,
    const float* __restrict__ bias3, const float* __restrict__ alpha,
    const float* __restrict__ res, int K, int lda, int ldb, int ldc) {
  __shared__ __align__(16) u16 As[2][128 * 32];   // 8KB x2
  __shared__ __align__(16) u16 Bs[2][128 * 32];   // 8KB x2  -> 32KB total

  const int tid = threadIdx.x;
  const int w = tid >> 6, lane = tid & 63;
  const int quad = lane >> 4, l16 = lane & 15;
  const int wm = w & 1, wn = w >> 1;

  // slot s (=0..511) covers LDS bytes s*16; row s>>2, col (s&3)*8 elems (pitch 32)
  const int slot0 = w * 128 + lane;
  const int slot1 = slot0 + 64;
  const u16* pA0 = A + (long)(blockIdx.x * 128 + (slot0 >> 2)) * lda + (slot0 & 3) * 8;
  const u16* pA1 = A + (long)(blockIdx.x * 128 + (slot1 >> 2)) * lda + (slot1 & 3) * 8;
  const u16* pB0 = Bt + (long)(blockIdx.y * 128 + (slot0 >> 2)) * ldb + (slot0 & 3) * 8;
  const u16* pB1 = Bt + (long)(blockIdx.y * 128 + (slot1 >> 2)) * ldb + (slot1 & 3) * 8;
  const int woff0 = w * 1024;          // wave-uniform dst offsets (u16 units)
  const int woff1 = woff0 + 512;

  const floatx4 z4 = {0.f, 0.f, 0.f, 0.f};
  floatx4 acc[4][4];
#pragma unroll
  for (int i = 0; i < 4; i++)
#pragma unroll
    for (int j = 0; j < 4; j++) acc[i][j] = z4;

  // prologue: stage tile 0 into buf 0
  gload16(pA0, &As[0][woff0]);
  gload16(pA1, &As[0][woff1]);
  gload16(pB0, &Bs[0][woff0]);
  gload16(pB1, &Bs[0][woff1]);
  pA0 += 32; pA1 += 32; pB0 += 32; pB1 += 32;
  __syncthreads();   // drains vmcnt -> buf0 visible

  int p = 0;
  for (int k0 = 0; k0 < K; k0 += 32) {
    if (k0 + 32 < K) {   // prefetch next tile into other buffer (issue-early)
      gload16(pA0, &As[p ^ 1][woff0]);
      gload16(pA1, &As[p ^ 1][woff1]);
      gload16(pB0, &Bs[p ^ 1][woff0]);
      gload16(pB1, &Bs[p ^ 1][woff1]);
      pA0 += 32; pA1 += 32; pB0 += 32; pB1 += 32;
    }

    bf16x8 af[4], bv[4];
#pragma unroll
    for (int mi = 0; mi < 4; mi++)
      af[mi] = *(const bf16x8*)&As[p][(wm * 64 + mi * 16 + l16) * 32 + quad * 8];
#pragma unroll
    for (int ni = 0; ni < 4; ni++)
      bv[ni] = *(const bf16x8*)&Bs[p][(wn * 64 + ni * 16 + l16) * 32 + quad * 8];
#pragma unroll
    for (int mi = 0; mi < 4; mi++)
#pragma unroll
      for (int ni = 0; ni < 4; ni++)
        acc[mi][ni] = __builtin_amdgcn_mfma_f32_16x16x32_bf16(af[mi], bv[ni], acc[mi][ni], 0, 0, 0);

    __syncthreads();   // drains prefetch vmcnt + all reads of buf p done
    p ^= 1;
  }

  const float* bptr = bias;
  if (SEG3) {
    const int seg = blockIdx.y >> 2;
    bptr = (seg == 0) ? bias : ((seg == 1) ? bias2 : bias3);
  }
  const long crow0 = (long)blockIdx.x * 128;
  const int ncol0 = blockIdx.y * 128 + wn * 64 + l16;
#pragma unroll
  for (int mi = 0; mi < 4; mi++) {
#pragma unroll
    for (int r = 0; r < 4; r++) {
      const int m = wm * 64 + mi * 16 + quad * 4 + r;
      const long rowbase = (crow0 + m) * (long)ldc;
      const float* rrow = (EPI == 3) ? (res + rowbase) : nullptr;
#pragma unroll
      for (int ni = 0; ni < 4; ni++) {
        const int n = ncol0 + ni * 16;
        float vv = acc[mi][ni][r] + bptr[SEG3 ? (n & 511) : n];
        if (EPI == 2) { if (vv < 0.f) vv *= alpha[n]; }
        if (EPI == 3) vv += rrow[n];
        if (FOUT) ((float*)Cv)[rowbase + n] = vv;
        else ((u16*)Cv)[rowbase + n] = f2bf(vv);
      }
    }
  }
}

// ---------------- bf16 TN GEMM, 128x64 tile, dbuf ----------------
template <int EPI, int FOUT>
__global__ __launch_bounds__(256, 3) void gemm_tn64(
    const u16* __restrict__ A, const u16* __restrict__ Bt, void* __restrict__ Cv,
    const float* __restrict__ bias, const float* __restrict__ alpha,
    const float* __restrict__ res, int K, int lda, int ldb, int ldc) {
  __shared__ __align__(16) u16 As[2][128 * 32];   // 8KB x2
  __shared__ __align__(16) u16 Bs[2][64 * 32];    // 4KB x2  -> 24KB total

  const int tid = threadIdx.x;
  const int w = tid >> 6, lane = tid & 63;
  const int quad = lane >> 4, l16 = lane & 15;

  const int rA0 = tid >> 2, cA = (tid & 3) * 8;   // A slots: tid, tid+256 (linear)
  const int rA1 = rA0 + 64;
  const u16* pA0 = A + (long)(blockIdx.x * 128 + rA0) * lda + cA;
  const u16* pA1 = A + (long)(blockIdx.x * 128 + rA1) * lda + cA;
  const u16* pB  = Bt + (long)(blockIdx.y * 64 + rA0) * ldb + cA;  // rA0<64 covers B
  const int aoff0 = w * 512;           // wave-uniform dst offsets (u16 units)
  const int aoff1 = aoff0 + 2048;
  const int boff  = w * 512;

  const floatx4 z4 = {0.f, 0.f, 0.f, 0.f};
  floatx4 acc[2][4];
#pragma unroll
  for (int i = 0; i < 2; i++)
#pragma unroll
    for (int j = 0; j < 4; j++) acc[i][j] = z4;

  // prologue: stage tile 0 into buf 0
  gload16(pA0, &As[0][aoff0]);
  gload16(pA1, &As[0][aoff1]);
  gload16(pB, &Bs[0][boff]);
  pA0 += 32; pA1 += 32; pB += 32;
  __syncthreads();

  int p = 0;
  for (int k0 = 0; k0 < K; k0 += 32) {
    if (k0 + 32 < K) {
      gload16(pA0, &As[p ^ 1][aoff0]);
      gload16(pA1, &As[p ^ 1][aoff1]);
      gload16(pB, &Bs[p ^ 1][boff]);
      pA0 += 32; pA1 += 32; pB += 32;
    }

    bf16x8 af[2], bv[4];
#pragma unroll
    for (int mi = 0; mi < 2; mi++)
      af[mi] = *(const bf16x8*)&As[p][(w * 32 + mi * 16 + l16) * 32 + quad * 8];
#pragma unroll
    for (int ni = 0; ni < 4; ni++)
      bv[ni] = *(const bf16x8*)&Bs[p][(ni * 16 + l16) * 32 + quad * 8];
#pragma unroll
    for (int mi = 0; mi < 2; mi++)
#pragma unroll
      for (int ni = 0; ni < 4; ni++)
        acc[mi][ni] = __builtin_amdgcn_mfma_f32_16x16x32_bf16(af[mi], bv[ni], acc[mi][ni], 0, 0, 0);

    __syncthreads();
    p ^= 1;
  }

  const long crow0 = (long)blockIdx.x * 128;
  const int ncol0 = blockIdx.y * 64 + l16;
#pragma unroll
  for (int mi = 0; mi < 2; mi++) {
#pragma unroll
    for (int r = 0; r < 4; r++) {
      const int m = w * 32 + mi * 16 + quad * 4 + r;
      const long rowbase = (crow0 + m) * (long)ldc;
      const float* rrow = (EPI == 3) ? (res + rowbase) : nullptr;
#pragma unroll
      for (int ni = 0; ni < 4; ni++) {
        const int n = ncol0 + ni * 16;
        float vv = acc[mi][ni][r] + bias[n];
        if (EPI == 2) { if (vv < 0.f) vv *= alpha[n]; }
        if (EPI == 3) vv += rrow[n];
        if (FOUT) ((float*)Cv)[rowbase + n] = vv;
        else ((u16*)Cv)[rowbase + n] = f2bf(vv);
      }
    }
  }
}

// ---------------- flash-fused attention (round-6 form + setprio + XCD grouping) ------
// 1-D grid of 512 blocks. Decode so all 32 q-tiles of one bh share one XCD
// (consecutive linear IDs round-robin XCDs; lin&7 pins the XCD group):
//   xcd = lin & 7; idx = lin >> 3; bh = xcd*2 + (idx>>5); qt = idx & 31.
// Each XCD then re-reads only its 2 bh's K/V (2 MB, L2-resident).
#define LDP 136
__global__ __launch_bounds__(256, 3) void k_attn(
    const u16* __restrict__ qkv, const u16* __restrict__ vt,
    const unsigned* __restrict__ mbits, u16* __restrict__ og) {
  __shared__ __align__(16) u16 KV[128 * LDP];
  __shared__ __align__(16) u16 Pl[64 * LDP];
  __shared__ unsigned Ml[64 * 4];

  const int tid = threadIdx.x;
  const int w = tid >> 6, lane = tid & 63;
  const int quad = lane >> 4, l16 = lane & 15;
  const int lin = blockIdx.x;
  const int xcd = lin & 7;
  const int idx = lin >> 3;
  const int z = xcd * 2 + (idx >> 5);   // bh
  const int qt = idx & 31;
  const int b = z >> 2, h = z & 3;

  const u16* qbase = qkv + (long)b * 2048 * 1536 + h * 128;        // cols 0..511
  const u16* kbase = qbase + 512;                                   // cols 512..1023
  const u16* vbase = vt + (long)(b * 4 + h) * 128 * 2048;           // [dh][kv]
  const unsigned* mbase = mbits + ((long)b * 2048 + qt * 64) * 64;

  // Q fragments in registers: wave w owns q-rows [w*16, w*16+16)
  bf16x8 qf[4];
#pragma unroll
  for (int ks = 0; ks < 4; ks++)
    qf[ks] = *(const bf16x8*)(qbase +
        (long)(qt * 64 + w * 16 + l16) * 1536 + ks * 32 + quad * 8);

  const floatx4 z4 = {0.f, 0.f, 0.f, 0.f};
  floatx4 Oacc[8];
#pragma unroll
  for (int ni = 0; ni < 8; ni++) Oacc[ni] = z4;
  float mrow[4], lrow[4];
#pragma unroll
  for (int r = 0; r < 4; r++) { mrow[r] = -3.4e38f; lrow[r] = 0.f; }

  const float scale = 0.08838834764831845f;
  const int srow = tid >> 4;            // staging row base
  const int scol = (tid & 15) * 8;      // staging col (elems)

  for (int kt = 0; kt < 16; kt++) {
    __syncthreads();  // prior PV reads of KV/Pl done
    // stage K-tile [kv][dh] + mask words (64 rows x 4 words = 256 = blockDim)
#pragma unroll
    for (int rr = 0; rr < 128; rr += 16)
      *(int4*)&KV[(rr + srow) * LDP + scol] =
          *(const int4*)(kbase + (long)(kt * 128 + rr + srow) * 1536 + scol);
    Ml[tid] = mbase[(tid >> 2) * 64 + kt * 4 + (tid & 3)];
    __syncthreads();

    // QK^T (setprio: favor MFMA-phase waves over co-resident staging blocks)
    floatx4 accS[8];
#pragma unroll
    for (int ni = 0; ni < 8; ni++) accS[ni] = z4;
    __builtin_amdgcn_s_setprio(1);
#pragma unroll
    for (int ks = 0; ks < 4; ks++) {
      bf16x8 bf[8];
#pragma unroll
      for (int ni = 0; ni < 8; ni++)
        bf[ni] = *(const bf16x8*)&KV[(ni * 16 + l16) * LDP + ks * 32 + quad * 8];
#pragma unroll
      for (int ni = 0; ni < 8; ni++)
        accS[ni] = __builtin_amdgcn_mfma_f32_16x16x32_bf16(qf[ks], bf[ni], accS[ni], 0, 0, 0);
    }
    __builtin_amdgcn_s_setprio(0);
    __syncthreads();  // KV reads done -> stage V

    // stage V-tile [dh][kv]
#pragma unroll
    for (int rr = 0; rr < 128; rr += 16)
      *(int4*)&KV[(rr + srow) * LDP + scol] =
          *(const int4*)(vbase + (long)(rr + srow) * 2048 + kt * 128 + scol);

    // online softmax (concurrent with V staging; Pl is wave-private)
#pragma unroll
    for (int r = 0; r < 4; r++) {
      const int rowl = w * 16 + quad * 4 + r;
      float s[8];
      float rmax = -1e30f;
#pragma unroll
      for (int ni = 0; ni < 8; ni++) {
        const unsigned mw = Ml[rowl * 4 + (ni >> 1)];
        const int on = (mw >> ((ni & 1) * 16 + l16)) & 1;
        s[ni] = on ? accS[ni][r] * scale : -1e30f;
        rmax = fmaxf(rmax, s[ni]);
      }
#pragma unroll
      for (int off = 1; off < 16; off <<= 1) rmax = fmaxf(rmax, __shfl_xor(rmax, off, 64));
      const float mnew = fmaxf(mrow[r], rmax);
      const float al = __expf(mrow[r] - mnew);
      float rs = 0.f;
#pragma unroll
      for (int ni = 0; ni < 8; ni++) {
        const float pp = __expf(s[ni] - mnew);
        rs += pp;
        Pl[rowl * LDP + ni * 16 + l16] = f2bf(pp);
      }
#pragma unroll
      for (int off = 1; off < 16; off <<= 1) rs += __shfl_xor(rs, off, 64);
      lrow[r] = lrow[r] * al + rs;
      mrow[r] = mnew;
#pragma unroll
      for (int ni = 0; ni < 8; ni++) Oacc[ni][r] *= al;
    }
    __syncthreads();  // V staged + P written

    // PV (setprio around MFMA cluster)
    __builtin_amdgcn_s_setprio(1);
#pragma unroll
    for (int ks = 0; ks < 4; ks++) {
      bf16x8 bv[8];
#pragma unroll
      for (int ni = 0; ni < 8; ni++)
        bv[ni] = *(const bf16x8*)&KV[(ni * 16 + l16) * LDP + ks * 32 + quad * 8];
      bf16x8 pf = *(const bf16x8*)&Pl[(w * 16 + l16) * LDP + ks * 32 + quad * 8];
#pragma unroll
      for (int ni = 0; ni < 8; ni++)
        Oacc[ni] = __builtin_amdgcn_mfma_f32_16x16x32_bf16(pf, bv[ni], Oacc[ni], 0, 0, 0);
    }
    __builtin_amdgcn_s_setprio(0);
  }

  // epilogue: divide by l, store o[b,q,h,dh] bf16
#pragma unroll
  for (int r = 0; r < 4; r++) {
    const float inv = 1.f / lrow[r];
    const long q = qt * 64 + w * 16 + quad * 4 + r;
#pragma unroll
    for (int ni = 0; ni < 8; ni++)
      og[((long)b * 2048 + q) * 512 + h * 128 + ni * 16 + l16] = f2bf(Oacc[ni][r] * inv);
  }
}

// ---------------- fused prep: build_x(xb, f32x4) + maskpack + weight transposes ------
// Linearized grid: [0,4096) build xb (4 elems/thread); [4096,6144) maskpack
// (grid-strided); [6144,12288) weight-transpose tiles (3072 per P-slab).
__global__ __launch_bounds__(256) void k_prep(
    const float* __restrict__ vents, const int* __restrict__ rels,
    const float* __restrict__ renc, u16* __restrict__ xb,
    const int* __restrict__ adjs, unsigned* __restrict__ bits,
    const float* __restrict__ Wq, const float* __restrict__ Wk,
    const float* __restrict__ Wv, const float* __restrict__ Wo,
    const float* __restrict__ W1, const float* __restrict__ W2,
    u16* __restrict__ wt) {
  __shared__ u16 tile[32][33];
  const int blk = blockIdx.x;
  if (blk < 4096) {
    // build xb, 4 elems/thread (f32x4 read, 4xbf16 packed 8B write)
    const long idx = ((long)blk * 256 + threadIdx.x) * 4;
    const int c = (int)(idx & 511);
    const int row = (int)(idx >> 9);
    const int b = row >> 11, n = row & 2047;
    float4 v4;
    if (n < 1600) v4 = *(const float4*)(vents + ((long)b * 1600 + n) * 512 + c);
    else v4 = *(const float4*)(renc + (long)rels[b * 448 + (n - 1600)] * 512 + c);
    const unsigned lo = (unsigned)f2bf(v4.x) | ((unsigned)f2bf(v4.y) << 16);
    const unsigned hi = (unsigned)f2bf(v4.z) | ((unsigned)f2bf(v4.w) << 16);
    *(uint2*)(xb + idx) = make_uint2(lo, hi);
  } else if (blk < 6144) {
    // maskpack, grid-strided over 262144 waves
    const int lane = threadIdx.x & 63;
    const int wbase = (blk - 4096) * 4 + (threadIdx.x >> 6);
    for (int wid = wbase; wid < 262144; wid += 2048 * 4) {
      const unsigned long long bal = __ballot(adjs[(long)wid * 64 + lane] != 0);
      if (lane == 0) {
        bits[wid * 2] = (unsigned)bal;
        bits[wid * 2 + 1] = (unsigned)(bal >> 32);
      }
    }
  } else {
    // weight transposes: t in [0,6144)
    int t = blk - 6144;
    const int pz = (t >= 3072) ? 1 : 0;
    t -= pz * 3072;
    const float* src;
    u16* dst;
    int ld_s, ld_d, bx, by;
    if (t < 1024) {                       // Wq/Wk/Wv/Wo: 512x512, grid 16x16
      const int wsel = t >> 8, tt = t & 255;
      const float* ws = (wsel == 0) ? Wq : (wsel == 1) ? Wk : (wsel == 2) ? Wv : Wo;
      src = ws + (long)pz * 262144;
      dst = wt + (long)pz * 3145728 + wsel * 262144;
      ld_s = 512; ld_d = 512;
      bx = tt & 15; by = tt >> 4;
    } else if (t < 2048) {                // W1: 512x2048 -> dst [2048][512]
      const int tt = t - 1024;
      src = W1 + (long)pz * 1048576;
      dst = wt + (long)pz * 3145728 + 1048576;
      ld_s = 2048; ld_d = 512;
      bx = tt & 15; by = tt >> 4;         // bx rows (16), by cols (64)
    } else {                              // W2: 2048x512 -> dst [512][2048]
      const int tt = t - 2048;
      src = W2 + (long)pz * 1048576;
      dst = wt + (long)pz * 3145728 + 2097152;
      ld_s = 512; ld_d = 2048;
      bx = tt >> 4; by = tt & 15;         // bx rows (64), by cols (16)
    }
    const int r0 = bx << 5, c0 = by << 5;
    const int tx = threadIdx.x & 31, ty = threadIdx.x >> 5;
#pragma unroll
    for (int i = 0; i < 32; i += 8)
      tile[ty + i][tx] = f2bf(src[(long)(r0 + ty + i) * ld_s + c0 + tx]);
    __syncthreads();
#pragma unroll
    for (int i = 0; i < 32; i += 8)
      dst[(long)(c0 + ty + i) * ld_d + r0 + tx] = tile[tx][ty + i];
  }
}

// ---------------- bf16 transpose for V ----------------
__global__ __launch_bounds__(256) void tr_bf16(const u16* __restrict__ src, u16* __restrict__ dst,
                                               int ld_src, int ld_dst, int zdiv,
                                               long s_out, long s_in, long d_out, long d_in_) {
  __shared__ u16 tile[32][33];
  const int zz = blockIdx.z, zq = zz / zdiv, zr = zz % zdiv;
  src += (long)zq * s_out + (long)zr * s_in;
  dst += (long)zq * d_out + (long)zr * d_in_;
  const int r0 = blockIdx.x << 5, c0 = blockIdx.y << 5;
  const int tx = threadIdx.x & 31, ty = threadIdx.x >> 5;
#pragma unroll
  for (int i = 0; i < 32; i += 8) tile[ty + i][tx] = src[(long)(r0 + ty + i) * ld_src + c0 + tx];
  __syncthreads();
#pragma unroll
  for (int i = 0; i < 32; i += 8) dst[(long)(c0 + ty + i) * ld_dst + r0 + tx] = tile[tx][ty + i];
}

// ---------------- LayerNorm 512 (float2-vectorized): f32 -> optional f32/bf16 --------
template <int WF32, int WBF>
__global__ __launch_bounds__(256) void k_ln(const float* __restrict__ in, float* __restrict__ out,
                                            u16* __restrict__ outb,
                                            const float* __restrict__ g, const float* __restrict__ bb) {
  __shared__ float rs[256], rq[256];
  const int row = blockIdx.x, tid = threadIdx.x;
  const float2 a = *(const float2*)(in + (long)row * 512 + tid * 2);
  rs[tid] = a.x + a.y;
  rq[tid] = a.x * a.x + a.y * a.y;
  __syncthreads();
  for (int s = 128; s > 0; s >>= 1) {
    if (tid < s) { rs[tid] += rs[tid + s]; rq[tid] += rq[tid + s]; }
    __syncthreads();
  }
  const float mu = rs[0] * (1.f / 512.f);
  const float var = rq[0] * (1.f / 512.f) - mu * mu;
  const float inv = 1.0f / sqrtf(var + 1e-5f);
  const float2 gg = *(const float2*)(g + tid * 2);
  const float2 b2 = *(const float2*)(bb + tid * 2);
  const float o0 = (a.x - mu) * inv * gg.x + b2.x;
  const float o1 = (a.y - mu) * inv * gg.y + b2.y;
  if (WF32) {
    *(float2*)(out + (long)row * 512 + tid * 2) = make_float2(o0, o1);
  }
  if (WBF) {
    const unsigned pk = (unsigned)f2bf(o0) | ((unsigned)f2bf(o1) << 16);
    *(unsigned*)(outb + (long)row * 512 + tid * 2) = pk;
  }
}

// ---------------- out: fill glob (from gents already in d_out) + emask ----------------
__global__ __launch_bounds__(256) void k_out2(const float* __restrict__ gents,
                                              const int* __restrict__ entlen,
                                              float* __restrict__ out, long out_n) {
  const long G = 2048, GE = 2048 + 4194304;
  const long idx = (long)blockIdx.x * 256 + threadIdx.x;
  if (idx < G) {
    const int b = (int)(idx >> 9), c = (int)(idx & 511);
    int e = entlen[0];
    if (e < 0 || e >= 2048) e = 1600;
    out[idx] = gents[((long)b * 2048 + e) * 512 + c];
  } else {
    const long oi = GE + (idx - G);
    if (oi < out_n) out[oi] = 1.0f;
  }
}

extern "C" void kernel_launch(void* const* d_in, const int* in_sizes, int n_in,
                              void* d_out, int out_size, void* d_ws, size_t ws_size,
                              hipStream_t stream) {
  const int* adjs = (const int*)d_in[0];
  const int* rels = (const int*)d_in[1];
  const float* vents = (const float*)d_in[2];
  const int* entlen = (const int*)d_in[3];
  const float* renc = (const float*)d_in[4];
  const float* Wq = (const float*)d_in[5];
  const float* Wk = (const float*)d_in[6];
  const float* Wv = (const float*)d_in[7];
  const float* Wo = (const float*)d_in[8];
  const float* W1 = (const float*)d_in[9];
  const float* W2 = (const float*)d_in[10];
  const float* bq = (const float*)d_in[11];
  const float* bk = (const float*)d_in[12];
  const float* bv = (const float*)d_in[13];
  const float* bo = (const float*)d_in[14];
  const float* b1 = (const float*)d_in[15];
  const float* b2 = (const float*)d_in[16];
  const float* ln1g = (const float*)d_in[17];
  const float* ln1b = (const float*)d_in[18];
  const float* ln2g = (const float*)d_in[19];
  const float* ln2b = (const float*)d_in[20];
  const float* prelu = (const float*)d_in[21];

  char* base = (char*)d_ws;
  float* t_f   = (float*)(base + 16777216);    // 16 MB
  float* tmp_f = (float*)(base + 33554432);    // 16 MB
  u16* wt  = (u16*)(base + 50331648);          // 12 MB
  u16* xb  = (u16*)(base + 62914560);          // 8 MB each
  u16* tb  = (u16*)(base + 71303168);
  u16* qkv = (u16*)(base + 79691776);          // 24 MB: [8192][1536] fused Q|K|V
  u16* Vtb = (u16*)(base + 104857600);         // 8 MB
  u16* ob  = (u16*)(base + 113246208);         // 8 MB
  u16* hb  = (u16*)(base + 121634816);         // 32 MB
  unsigned* mbits = (unsigned*)(base + 155189248);  // 2 MB

  float* out_f = (float*)d_out;
  float* gents = out_f + 2048;                 // gents region of d_out

  // fused prep: xb + mask bits + all weight transposes (one dispatch)
  k_prep<<<dim3(12288), 256, 0, stream>>>(vents, rels, renc, xb, adjs, mbits,
                                          Wq, Wk, Wv, Wo, W1, W2, wt);

  for (int j = 0; j < 2; j++) {
    const u16* wqt = wt + (long)j * 3145728;   // [1536 x 512] fused QKV (contiguous)
    const u16* wot = wqt + 786432;
    const u16* w1t = wqt + 1048576;
    const u16* w2t = wqt + 2097152;

    // fused QKV: [8192x512] @ [512x1536] -> qkv[8192][1536], bias per 512-segment
    gemm_tn<1, 0, 1><<<dim3(64, 12), 256, 0, stream>>>(
        xb, wqt, qkv, bq + j * 512, bk + j * 512, bv + j * 512, nullptr, nullptr,
        512, 512, 512, 1536);

    // Vtb[b,h,dh,kv] = qkv[b,kv, 1024 + h*128 + dh]
    tr_bf16<<<dim3(64, 4, 16), 256, 0, stream>>>(qkv + 1024, Vtb, 1536, 2048, 4,
        3145728L, 128L, 1048576L, 262144L);

    // fused attention -> ob (1-D XCD-grouped grid)
    k_attn<<<dim3(512), 256, 0, stream>>>(qkv, Vtb, mbits, ob);

    // attn_out(f32) = ob @ Wo + bo -> tmp
    gemm_tn64<1, 1><<<dim3(64, 8), 256, 0, stream>>>(ob, wot, tmp_f, bo + j * 512, nullptr, nullptr, 512, 512, 512, 512);
    // t = LN1(tmp) -> t_f (residual) + tb (bf16 for W1)
    k_ln<1, 1><<<dim3(8192), 256, 0, stream>>>(tmp_f, t_f, tb, ln1g + j * 512, ln1b + j * 512);
    // hb(bf16) = PReLU(t @ W1 + b1)
    gemm_tn<2, 0, 0><<<dim3(64, 16), 256, 0, stream>>>(tb, w1t, hb, b1 + j * 2048, nullptr, nullptr, prelu + j * 2048, nullptr, 512, 512, 512, 2048);
    // tmp(f32) = hb @ W2 + b2 + t_f
    gemm_tn64<3, 1><<<dim3(64, 8), 256, 0, stream>>>(hb, w2t, tmp_f, b2 + j * 512, nullptr, t_f, 2048, 2048, 2048, 512);
    // x = LN2(tmp): layer 0 -> xb only (f32 x was dead); layer 1 -> gents in d_out
    if (j == 0)
      k_ln<0, 1><<<dim3(8192), 256, 0, stream>>>(tmp_f, nullptr, xb, ln2g + j * 512, ln2b + j * 512);
    else
      k_ln<1, 0><<<dim3(8192), 256, 0, stream>>>(tmp_f, gents, nullptr, ln2g + j * 512, ln2b + j * 512);
  }

  // fill glob (gather from gents already in d_out) + emask
  const long out_n = (long)out_size;
  k_out2<<<dim3(40), 256, 0, stream>>>(gents, entlen, out_f, out_n);
}